// Round 1
// baseline (4365.362 us; speedup 1.0000x reference)
//
#include <hip/hip_runtime.h>
#include <math.h>

// Problem constants (from setup_inputs): B=4, Nq=2048, Nf=16384, D=3, C=768
#define Bt  4
#define NQ  2048
#define NF  16384
#define CC  768
#define TQ  16      // query rows per block
#define BLK 256     // threads per block

static __device__ __forceinline__ float relu(float x) { return fmaxf(x, 0.0f); }

// ---------------------------------------------------------------------------
// Kernel 1: kp[b,m,:] = relu(k[b,m,:] @ W2^T + b2), stored as padded float4
// ---------------------------------------------------------------------------
__global__ __launch_bounds__(256) void kp_kernel(
    const float* __restrict__ k, const float* __restrict__ W2,
    const float* __restrict__ b2, float4* __restrict__ kp)
{
    int idx = blockIdx.x * 256 + threadIdx.x;   // over B*NF rows (exact grid)
    float x0 = k[(size_t)idx * 3 + 0];
    float x1 = k[(size_t)idx * 3 + 1];
    float x2 = k[(size_t)idx * 3 + 2];
    float4 r;
    r.x = relu(fmaf(W2[0], x0, fmaf(W2[1], x1, fmaf(W2[2], x2, b2[0]))));
    r.y = relu(fmaf(W2[3], x0, fmaf(W2[4], x1, fmaf(W2[5], x2, b2[1]))));
    r.z = relu(fmaf(W2[6], x0, fmaf(W2[7], x1, fmaf(W2[8], x2, b2[2]))));
    r.w = 0.0f;
    kp[idx] = r;
}

// ---------------------------------------------------------------------------
// Kernel 2: fused attention. One block = (batch b, 16 query rows).
// 3 passes over Nf: rowmax, sumexp, p@V accumulate (p staged in LDS).
// Thread t owns output channels {t, t+256, t+512} for all 16 rows.
// ---------------------------------------------------------------------------
__global__ __launch_bounds__(BLK) void attn_kernel(
    const float* __restrict__ q, const float4* __restrict__ kp,
    const float* __restrict__ v, const float* __restrict__ W1,
    const float* __restrict__ b1, float* __restrict__ out)
{
    // 260 = 4*65: rows 16-byte aligned so float4 reads at mm%4==0 are legal
    __shared__ float pbuf[TQ][260];
    __shared__ float wredA[4][TQ];
    __shared__ float wredB[4][TQ];

    const float SCALE = 0.57735026918962576f;  // 1/sqrt(3)

    const int b    = blockIdx.x / (NQ / TQ);
    const int q0   = (blockIdx.x % (NQ / TQ)) * TQ;
    const int t    = threadIdx.x;
    const int wave = t >> 6;
    const int lane = t & 63;

    // ---- per-block: compute qp (scaled by SCALE) for the 16 rows, in regs ----
    const float w0 = W1[0], w1 = W1[1], w2 = W1[2];
    const float w3 = W1[3], w4 = W1[4], w5 = W1[5];
    const float w6 = W1[6], w7 = W1[7], w8 = W1[8];
    const float bb0 = b1[0], bb1 = b1[1], bb2 = b1[2];

    float qpx[TQ], qpy[TQ], qpz[TQ];
#pragma unroll
    for (int i = 0; i < TQ; ++i) {
        const float* qr = q + (size_t)(b * NQ + q0 + i) * 3;
        float x0 = qr[0], x1 = qr[1], x2 = qr[2];
        qpx[i] = relu(fmaf(w0, x0, fmaf(w1, x1, fmaf(w2, x2, bb0)))) * SCALE;
        qpy[i] = relu(fmaf(w3, x0, fmaf(w4, x1, fmaf(w5, x2, bb1)))) * SCALE;
        qpz[i] = relu(fmaf(w6, x0, fmaf(w7, x1, fmaf(w8, x2, bb2)))) * SCALE;
    }

    const float4* kpb = kp + (size_t)b * NF;

    // ---- pass 1: row max over all Nf scores ----
    float pmax[TQ];
#pragma unroll
    for (int i = 0; i < TQ; ++i) pmax[i] = -1e30f;
    for (int m = t; m < NF; m += BLK) {
        float4 kk = kpb[m];
#pragma unroll
        for (int i = 0; i < TQ; ++i) {
            float s = fmaf(qpx[i], kk.x, fmaf(qpy[i], kk.y, qpz[i] * kk.z));
            pmax[i] = fmaxf(pmax[i], s);
        }
    }
#pragma unroll
    for (int off = 32; off >= 1; off >>= 1) {
#pragma unroll
        for (int i = 0; i < TQ; ++i)
            pmax[i] = fmaxf(pmax[i], __shfl_xor(pmax[i], off, 64));
    }
    if (lane == 0) {
#pragma unroll
        for (int i = 0; i < TQ; ++i) wredA[wave][i] = pmax[i];
    }
    __syncthreads();
    float rowmax[TQ];
#pragma unroll
    for (int i = 0; i < TQ; ++i)
        rowmax[i] = fmaxf(fmaxf(wredA[0][i], wredA[1][i]),
                          fmaxf(wredA[2][i], wredA[3][i]));

    // ---- pass 2: sum of exp(s - rowmax) ----
    float psum[TQ];
#pragma unroll
    for (int i = 0; i < TQ; ++i) psum[i] = 0.0f;
    for (int m = t; m < NF; m += BLK) {
        float4 kk = kpb[m];
#pragma unroll
        for (int i = 0; i < TQ; ++i) {
            float s = fmaf(qpx[i], kk.x, fmaf(qpy[i], kk.y, qpz[i] * kk.z));
            psum[i] += __expf(s - rowmax[i]);
        }
    }
#pragma unroll
    for (int off = 32; off >= 1; off >>= 1) {
#pragma unroll
        for (int i = 0; i < TQ; ++i)
            psum[i] += __shfl_xor(psum[i], off, 64);
    }
    if (lane == 0) {
#pragma unroll
        for (int i = 0; i < TQ; ++i) wredB[wave][i] = psum[i];
    }
    __syncthreads();
    float linv[TQ];
#pragma unroll
    for (int i = 0; i < TQ; ++i)
        linv[i] = 1.0f / (wredB[0][i] + wredB[1][i] + wredB[2][i] + wredB[3][i]);

    // ---- pass 3: accumulate out = sum_m exp(s_m - rowmax) * v[m, :] ----
    float acc0[TQ], acc1[TQ], acc2[TQ];
#pragma unroll
    for (int i = 0; i < TQ; ++i) { acc0[i] = 0.f; acc1[i] = 0.f; acc2[i] = 0.f; }

    const int c0 = t, c1 = t + 256, c2 = t + 512;
    const float* vb = v + (size_t)b * NF * CC;

    for (int m0 = 0; m0 < NF; m0 += BLK) {
        // each thread computes p for its column m0+t, all 16 rows, into LDS
        float4 kk = kpb[m0 + t];
#pragma unroll
        for (int i = 0; i < TQ; ++i) {
            float s = fmaf(qpx[i], kk.x, fmaf(qpy[i], kk.y, qpz[i] * kk.z));
            pbuf[i][t] = __expf(s - rowmax[i]);
        }
        __syncthreads();

        for (int mm = 0; mm < BLK; mm += 4) {
            const float* vr = vb + (size_t)(m0 + mm) * CC;
            float va0 = vr[c0],          vb0 = vr[c1],          vc0 = vr[c2];
            float va1 = vr[CC + c0],     vb1 = vr[CC + c1],     vc1 = vr[CC + c2];
            float va2 = vr[2 * CC + c0], vb2 = vr[2 * CC + c1], vc2 = vr[2 * CC + c2];
            float va3 = vr[3 * CC + c0], vb3 = vr[3 * CC + c1], vc3 = vr[3 * CC + c2];
#pragma unroll
            for (int i = 0; i < TQ; ++i) {
                float4 p = *(const float4*)&pbuf[i][mm];  // LDS broadcast, aligned
                acc0[i] = fmaf(p.x, va0, fmaf(p.y, va1, fmaf(p.z, va2, fmaf(p.w, va3, acc0[i]))));
                acc1[i] = fmaf(p.x, vb0, fmaf(p.y, vb1, fmaf(p.z, vb2, fmaf(p.w, vb3, acc1[i]))));
                acc2[i] = fmaf(p.x, vc0, fmaf(p.y, vc1, fmaf(p.z, vc2, fmaf(p.w, vc3, acc2[i]))));
            }
        }
        __syncthreads();
    }

    // ---- epilogue: normalize and store (coalesced) ----
#pragma unroll
    for (int i = 0; i < TQ; ++i) {
        float* orow = out + (size_t)(b * NQ + q0 + i) * CC;
        orow[c0] = acc0[i] * linv[i];
        orow[c1] = acc1[i] * linv[i];
        orow[c2] = acc2[i] * linv[i];
    }
}

// ---------------------------------------------------------------------------
extern "C" void kernel_launch(void* const* d_in, const int* in_sizes, int n_in,
                              void* d_out, int out_size, void* d_ws, size_t ws_size,
                              hipStream_t stream) {
    const float* q  = (const float*)d_in[0];
    const float* k  = (const float*)d_in[1];
    const float* v  = (const float*)d_in[2];
    const float* W1 = (const float*)d_in[3];
    const float* b1 = (const float*)d_in[4];
    const float* W2 = (const float*)d_in[5];
    const float* b2 = (const float*)d_in[6];
    float* out = (float*)d_out;

    // ws: kp as padded float4, B*NF*16 bytes = 1 MiB
    float4* kp = (float4*)d_ws;

    hipLaunchKernelGGL(kp_kernel, dim3((Bt * NF) / 256), dim3(256), 0, stream,
                       k, W2, b2, kp);
    hipLaunchKernelGGL(attn_kernel, dim3(Bt * (NQ / TQ)), dim3(BLK), 0, stream,
                       q, kp, v, W1, b1, out);
}

// Round 2
// 958.652 us; speedup vs baseline: 4.5536x; 4.5536x over previous
//
#include <hip/hip_runtime.h>
#include <math.h>

// Problem constants: B=4, Nq=2048, Nf=16384, D=3, C=768
#define Bt  4
#define NQ  2048
#define NF  16384
#define CC  768
#define QT  256     // q-rows per main block
#define CT  96      // channels per main block
#define BK  128     // Nf chunk per LDS stage
#define THR 512     // threads per main block

#define SCALE_LOG2E 0.8329080161227079f   // (1/sqrt(3)) * log2(e)

typedef __attribute__((ext_vector_type(8))) short short8;
typedef __attribute__((ext_vector_type(4))) float floatx4;

#if __has_builtin(__builtin_amdgcn_exp2f)
#define EXP2F(x) __builtin_amdgcn_exp2f(x)
#else
#define EXP2F(x) __expf((x) * 0.6931471805599453f)
#endif

static __device__ __forceinline__ float relu(float x) { return fmaxf(x, 0.0f); }

// fp32 -> bf16 bits, round-to-nearest-even (inputs are finite, non-NaN)
static __device__ __forceinline__ unsigned int f2bf(float f) {
    unsigned int u = __float_as_uint(f);
    u += 0x7fffu + ((u >> 16) & 1u);
    return u >> 16;
}

// ---------------------------------------------------------------------------
// Kernel 1 (prep): qp = relu(q@W1^T+b1)*SCALE*log2e ; kp = relu(k@W2^T+b2)
// Grid exactly covers B*NQ + B*NF rows.
// ---------------------------------------------------------------------------
__global__ __launch_bounds__(256) void prep_kernel(
    const float* __restrict__ q, const float* __restrict__ k,
    const float* __restrict__ W1, const float* __restrict__ b1,
    const float* __restrict__ W2, const float* __restrict__ b2,
    float4* __restrict__ qp, float4* __restrict__ kp)
{
    int idx = blockIdx.x * 256 + threadIdx.x;
    if (idx < Bt * NQ) {
        const float* r = q + (size_t)idx * 3;
        float x0 = r[0], x1 = r[1], x2 = r[2];
        float4 o;
        o.x = relu(fmaf(W1[0], x0, fmaf(W1[1], x1, fmaf(W1[2], x2, b1[0])))) * SCALE_LOG2E;
        o.y = relu(fmaf(W1[3], x0, fmaf(W1[4], x1, fmaf(W1[5], x2, b1[1])))) * SCALE_LOG2E;
        o.z = relu(fmaf(W1[6], x0, fmaf(W1[7], x1, fmaf(W1[8], x2, b1[2])))) * SCALE_LOG2E;
        o.w = 0.0f;
        qp[idx] = o;
    } else {
        int kidx = idx - Bt * NQ;   // < Bt*NF by grid construction
        const float* r = k + (size_t)kidx * 3;
        float x0 = r[0], x1 = r[1], x2 = r[2];
        float4 o;
        o.x = relu(fmaf(W2[0], x0, fmaf(W2[1], x1, fmaf(W2[2], x2, b2[0]))));
        o.y = relu(fmaf(W2[3], x0, fmaf(W2[4], x1, fmaf(W2[5], x2, b2[1]))));
        o.z = relu(fmaf(W2[6], x0, fmaf(W2[7], x1, fmaf(W2[8], x2, b2[2]))));
        o.w = 0.0f;
        kp[kidx] = o;
    }
}

// ---------------------------------------------------------------------------
// Kernel 2 (stats): per q-row rowmax' (log2 domain) and 1/sum(exp2).
// One block = (b, 16 q-rows). 512 blocks x 256 threads.
// ---------------------------------------------------------------------------
__global__ __launch_bounds__(256) void stats_kernel(
    const float4* __restrict__ qp, const float4* __restrict__ kp,
    float2* __restrict__ rstat)
{
    __shared__ float wredA[4][16];
    __shared__ float wredB[4][16];

    const int bid  = blockIdx.x;
    const int b    = bid >> 7;            // NQ/16 = 128 blocks per batch
    const int q0   = (bid & 127) * 16;
    const int t    = threadIdx.x;
    const int wv   = t >> 6;
    const int lane = t & 63;

    float qx[16], qy[16], qz[16];
#pragma unroll
    for (int i = 0; i < 16; ++i) {
        float4 qv = qp[b * NQ + q0 + i];
        qx[i] = qv.x; qy[i] = qv.y; qz[i] = qv.z;
    }
    const float4* kpb = kp + (size_t)b * NF;

    // pass 1: rowmax
    float pmax[16];
#pragma unroll
    for (int i = 0; i < 16; ++i) pmax[i] = -1e30f;
    for (int m = t; m < NF; m += 256) {
        float4 kk = kpb[m];
#pragma unroll
        for (int i = 0; i < 16; ++i) {
            float s = fmaf(qx[i], kk.x, fmaf(qy[i], kk.y, qz[i] * kk.z));
            pmax[i] = fmaxf(pmax[i], s);
        }
    }
#pragma unroll
    for (int off = 32; off >= 1; off >>= 1)
#pragma unroll
        for (int i = 0; i < 16; ++i)
            pmax[i] = fmaxf(pmax[i], __shfl_xor(pmax[i], off, 64));
    if (lane == 0)
#pragma unroll
        for (int i = 0; i < 16; ++i) wredA[wv][i] = pmax[i];
    __syncthreads();

    float rowmax[16];
#pragma unroll
    for (int i = 0; i < 16; ++i)
        rowmax[i] = fmaxf(fmaxf(wredA[0][i], wredA[1][i]),
                          fmaxf(wredA[2][i], wredA[3][i]));

    // pass 2: sum of exp2(s - rowmax)
    float psum[16];
#pragma unroll
    for (int i = 0; i < 16; ++i) psum[i] = 0.0f;
    for (int m = t; m < NF; m += 256) {
        float4 kk = kpb[m];
#pragma unroll
        for (int i = 0; i < 16; ++i) {
            float s = fmaf(qx[i], kk.x, fmaf(qy[i], kk.y, qz[i] * kk.z));
            psum[i] += EXP2F(s - rowmax[i]);
        }
    }
#pragma unroll
    for (int off = 32; off >= 1; off >>= 1)
#pragma unroll
        for (int i = 0; i < 16; ++i)
            psum[i] += __shfl_xor(psum[i], off, 64);
    if (lane == 0)
#pragma unroll
        for (int i = 0; i < 16; ++i) wredB[wv][i] = psum[i];
    __syncthreads();

    if (t < 16) {
        float m = fmaxf(fmaxf(wredA[0][t], wredA[1][t]),
                        fmaxf(wredA[2][t], wredA[3][t]));
        float l = wredB[0][t] + wredB[1][t] + wredB[2][t] + wredB[3][t];
        rstat[b * NQ + q0 + t] = make_float2(m, 1.0f / l);
    }
}

// ---------------------------------------------------------------------------
// Kernel 3 (main): out-tile 256q x 96c per block, MFMA bf16 over Nf.
// P computed in A-fragment registers; v staged transposed (k-major bf16) LDS.
// ---------------------------------------------------------------------------
__global__ __launch_bounds__(THR, 2) void attn_mfma_kernel(
    const float* __restrict__ v, const float4* __restrict__ qp,
    const float4* __restrict__ kp, const float2* __restrict__ rstat,
    float* __restrict__ out)
{
    // vT: 96 c-rows, each 68 dwords (136 bf16: 128 k + pad), stride 272 B
    __shared__ unsigned int vTdw[CT * 68];
    __shared__ float4 kpL[144];     // 128 entries + 1 pad float4 per 8 rows

    const int t    = threadIdx.x;
    const int bid  = blockIdx.x;
    // XCD-swizzle: 8 q-tiles of the same (b, ct) group land on one XCD
    const int g    = (bid & 7) + 8 * ((bid >> 3) & 3);  // 0..31 -> (b, ct)
    const int qt   = bid >> 5;                          // 0..7
    const int b    = g >> 3;
    const int ct   = g & 7;

    const int lane = t & 63;
    const int wv   = t >> 6;        // wave 0..7
    const int quad = lane >> 4;
    const int l15  = lane & 15;
    const int rg   = wv & 3;        // row-group (x64 rows)
    const int cg   = wv >> 2;       // col-group (x48 cols)

    const int qrow0 = b * NQ + qt * QT;
    const int cbase = ct * CT;

    // per-lane qp rows (A-operand rows) + rowmax'
    float qx[4], qy[4], qz[4], rm[4];
#pragma unroll
    for (int r = 0; r < 4; ++r) {
        int row = qrow0 + rg * 64 + r * 16 + l15;
        float4 qv = qp[row];
        qx[r] = qv.x; qy[r] = qv.y; qz[r] = qv.z;
        rm[r] = rstat[row].x;
    }

    // staging mapping: thread -> (row-pair rp, float4-col c4l + 8*rep)
    const int rp  = (t & 7) + 8 * wv;       // 0..63
    const int c4l = (t >> 3) & 7;           // 0..7

    const float*  vb  = v  + (size_t)b * NF * CC + cbase;
    const float4* kpb = kp + (size_t)b * NF;

    floatx4 acc[4][3];
#pragma unroll
    for (int r = 0; r < 4; ++r)
#pragma unroll
        for (int cb = 0; cb < 3; ++cb)
            acc[r][cb] = (floatx4){0.f, 0.f, 0.f, 0.f};

    float va0[3][4], va1[3][4];
    float4 kpld = make_float4(0.f, 0.f, 0.f, 0.f);

    // ---- load chunk 0 ----
#pragma unroll
    for (int rep = 0; rep < 3; ++rep) {
        int col = 4 * (c4l + 8 * rep);
        const float4* p0 = (const float4*)(vb + (size_t)(2 * rp) * CC + col);
        float4 a = p0[0];
        float4 bq = p0[CC / 4];
        va0[rep][0] = a.x;  va0[rep][1] = a.y;  va0[rep][2] = a.z;  va0[rep][3] = a.w;
        va1[rep][0] = bq.x; va1[rep][1] = bq.y; va1[rep][2] = bq.z; va1[rep][3] = bq.w;
    }
    if (t < BK) kpld = kpb[t];

    for (int ch = 0; ch < NF / BK; ++ch) {
        if (ch) __syncthreads();            // previous compute done with LDS

        // store staged chunk to LDS (v transposed bf16-pairs, kp padded AoS)
#pragma unroll
        for (int rep = 0; rep < 3; ++rep) {
            int c0 = 4 * (c4l + 8 * rep);
#pragma unroll
            for (int w = 0; w < 4; ++w) {
                unsigned int pk = f2bf(va0[rep][w]) | (f2bf(va1[rep][w]) << 16);
                vTdw[(c0 + w) * 68 + rp] = pk;
            }
        }
        if (t < BK) kpL[t + (t >> 3)] = kpld;
        __syncthreads();

        // prefetch next chunk into registers (overlaps with compute below)
        if (ch + 1 < NF / BK) {
            int m0 = (ch + 1) * BK;
#pragma unroll
            for (int rep = 0; rep < 3; ++rep) {
                int col = 4 * (c4l + 8 * rep);
                const float4* p0 = (const float4*)(vb + (size_t)(m0 + 2 * rp) * CC + col);
                float4 a = p0[0];
                float4 bq = p0[CC / 4];
                va0[rep][0] = a.x;  va0[rep][1] = a.y;  va0[rep][2] = a.z;  va0[rep][3] = a.w;
                va1[rep][0] = bq.x; va1[rep][1] = bq.y; va1[rep][2] = bq.z; va1[rep][3] = bq.w;
            }
            if (t < BK) kpld = kpb[m0 + t];
        }

        // ---- compute 4 K32 steps over this chunk ----
#pragma unroll
        for (int kk = 0; kk < BK; kk += 32) {
            // kp for this lane's 8 k's (quad-broadcast reads from padded LDS)
            float4 kq[8];
            int kbase = kk + (kk >> 3) + 9 * quad;
#pragma unroll
            for (int j = 0; j < 8; ++j) kq[j] = kpL[kbase + j];

            // B-fragments: vT[c][kk + quad*8 .. +7], contiguous 16 B
            union { uint4 u; short8 s; } bw[3];
#pragma unroll
            for (int cb = 0; cb < 3; ++cb) {
                int c = cg * 48 + cb * 16 + l15;
                bw[cb].u = *(const uint4*)&vTdw[c * 68 + (kk >> 1) + quad * 4];
            }

#pragma unroll
            for (int r = 0; r < 4; ++r) {
                short8 af;
#pragma unroll
                for (int j = 0; j < 8; ++j) {
                    float s = fmaf(qx[r], kq[j].x,
                              fmaf(qy[r], kq[j].y, qz[r] * kq[j].z)) - rm[r];
                    af[j] = (short)f2bf(EXP2F(s));
                }
#pragma unroll
                for (int cb = 0; cb < 3; ++cb)
                    acc[r][cb] = __builtin_amdgcn_mfma_f32_16x16x32_bf16(
                        af, bw[cb].s, acc[r][cb], 0, 0, 0);
            }
        }
    }

    // ---- epilogue: normalize (linv) and store ----
#pragma unroll
    for (int r = 0; r < 4; ++r) {
#pragma unroll
        for (int vv = 0; vv < 4; ++vv) {
            int row = qrow0 + rg * 64 + r * 16 + quad * 4 + vv;
            float lv = rstat[row].y;
            size_t obase = (size_t)row * CC + cbase + cg * 48 + l15;
#pragma unroll
            for (int cb = 0; cb < 3; ++cb)
                out[obase + cb * 16] = acc[r][cb][vv] * lv;
        }
    }
}

// ---------------------------------------------------------------------------
extern "C" void kernel_launch(void* const* d_in, const int* in_sizes, int n_in,
                              void* d_out, int out_size, void* d_ws, size_t ws_size,
                              hipStream_t stream) {
    const float* q  = (const float*)d_in[0];
    const float* k  = (const float*)d_in[1];
    const float* v  = (const float*)d_in[2];
    const float* W1 = (const float*)d_in[3];
    const float* b1 = (const float*)d_in[4];
    const float* W2 = (const float*)d_in[5];
    const float* b2 = (const float*)d_in[6];
    float* out = (float*)d_out;

    // ws layout: kp (1 MiB) | qp (128 KiB) | rstat (64 KiB)
    float4* kpW   = (float4*)d_ws;
    float4* qpW   = (float4*)((char*)d_ws + (size_t)Bt * NF * 16);
    float2* rstat = (float2*)((char*)d_ws + (size_t)Bt * NF * 16 + (size_t)Bt * NQ * 16);

    hipLaunchKernelGGL(prep_kernel, dim3((Bt * NQ + Bt * NF) / 256), dim3(256), 0, stream,
                       q, k, W1, b1, W2, b2, qpW, kpW);
    hipLaunchKernelGGL(stats_kernel, dim3(Bt * (NQ / 16)), dim3(256), 0, stream,
                       qpW, kpW, rstat);
    hipLaunchKernelGGL(attn_mfma_kernel, dim3(Bt * (NQ / QT) * (CC / CT)), dim3(THR), 0, stream,
                       v, qpW, kpW, rstat, out);
}

// Round 3
// 764.707 us; speedup vs baseline: 5.7085x; 1.2536x over previous
//
#include <hip/hip_runtime.h>
#include <math.h>

// Problem constants: B=4, Nq=2048, Nf=16384, D=3, C=768
#define Bt  4
#define NQ  2048
#define NF  16384
#define CC  768
#define QT  128     // q-rows per main block
#define CT  96      // channels per main block
#define BK  128     // Nf chunk per LDS stage
#define THR 512     // threads per main block
#define NCH (NF / BK)

#define SCALE_LOG2E 0.8329080161227079f   // (1/sqrt(3)) * log2(e)

typedef __attribute__((ext_vector_type(8))) short short8;
typedef __attribute__((ext_vector_type(4))) float floatx4;

#if __has_builtin(__builtin_amdgcn_exp2f)
#define EXP2F(x) __builtin_amdgcn_exp2f(x)
#else
#define EXP2F(x) __expf((x) * 0.6931471805599453f)
#endif

static __device__ __forceinline__ float relu(float x) { return fmaxf(x, 0.0f); }

// fp32 -> bf16 bits, round-to-nearest-even (inputs finite, non-NaN)
static __device__ __forceinline__ unsigned int f2bf(float f) {
    unsigned int u = __float_as_uint(f);
    u += 0x7fffu + ((u >> 16) & 1u);
    return u >> 16;
}

// ---------------------------------------------------------------------------
// Kernel 1 (prep): qp = relu(q@W1^T+b1)*SCALE*log2e (float4, w=0 placeholder)
//                  kp = relu(k@W2^T+b2) stored TIGHT float3
// ---------------------------------------------------------------------------
__global__ __launch_bounds__(256) void prep_kernel(
    const float* __restrict__ q, const float* __restrict__ k,
    const float* __restrict__ W1, const float* __restrict__ b1,
    const float* __restrict__ W2, const float* __restrict__ b2,
    float4* __restrict__ qp, float* __restrict__ kp3)
{
    int idx = blockIdx.x * 256 + threadIdx.x;
    if (idx < Bt * NQ) {
        const float* r = q + (size_t)idx * 3;
        float x0 = r[0], x1 = r[1], x2 = r[2];
        float4 o;
        o.x = relu(fmaf(W1[0], x0, fmaf(W1[1], x1, fmaf(W1[2], x2, b1[0])))) * SCALE_LOG2E;
        o.y = relu(fmaf(W1[3], x0, fmaf(W1[4], x1, fmaf(W1[5], x2, b1[1])))) * SCALE_LOG2E;
        o.z = relu(fmaf(W1[6], x0, fmaf(W1[7], x1, fmaf(W1[8], x2, b1[2])))) * SCALE_LOG2E;
        o.w = 0.0f;
        qp[idx] = o;
    } else {
        int kidx = idx - Bt * NQ;   // < Bt*NF by grid construction
        const float* r = k + (size_t)kidx * 3;
        float x0 = r[0], x1 = r[1], x2 = r[2];
        float* dst = kp3 + (size_t)kidx * 3;
        dst[0] = relu(fmaf(W2[0], x0, fmaf(W2[1], x1, fmaf(W2[2], x2, b2[0]))));
        dst[1] = relu(fmaf(W2[3], x0, fmaf(W2[4], x1, fmaf(W2[5], x2, b2[1]))));
        dst[2] = relu(fmaf(W2[6], x0, fmaf(W2[7], x1, fmaf(W2[8], x2, b2[2]))));
    }
}

// ---------------------------------------------------------------------------
// Kernel 2 (stats): rowmax' (log2 domain) and 1/sum(exp2). Writes qp.w = -rm
// so the main kernel's score fma-chain includes the shift for free.
// ---------------------------------------------------------------------------
__global__ __launch_bounds__(256) void stats_kernel(
    float4* __restrict__ qp, const float* __restrict__ kp3,
    float2* __restrict__ rstat)
{
    __shared__ float wredA[4][16];
    __shared__ float wredB[4][16];

    const int bid  = blockIdx.x;
    const int b    = bid >> 7;            // NQ/16 = 128 blocks per batch
    const int q0   = (bid & 127) * 16;
    const int t    = threadIdx.x;
    const int wv   = t >> 6;
    const int lane = t & 63;

    float qx[16], qy[16], qz[16];
#pragma unroll
    for (int i = 0; i < 16; ++i) {
        float4 qv = qp[b * NQ + q0 + i];
        qx[i] = qv.x; qy[i] = qv.y; qz[i] = qv.z;
    }
    const float* kpb = kp3 + (size_t)b * NF * 3;

    // pass 1: rowmax
    float pmax[16];
#pragma unroll
    for (int i = 0; i < 16; ++i) pmax[i] = -1e30f;
    for (int m = t; m < NF; m += 256) {
        float kx = kpb[3 * m], ky = kpb[3 * m + 1], kz = kpb[3 * m + 2];
#pragma unroll
        for (int i = 0; i < 16; ++i) {
            float s = fmaf(qx[i], kx, fmaf(qy[i], ky, qz[i] * kz));
            pmax[i] = fmaxf(pmax[i], s);
        }
    }
#pragma unroll
    for (int off = 32; off >= 1; off >>= 1)
#pragma unroll
        for (int i = 0; i < 16; ++i)
            pmax[i] = fmaxf(pmax[i], __shfl_xor(pmax[i], off, 64));
    if (lane == 0)
#pragma unroll
        for (int i = 0; i < 16; ++i) wredA[wv][i] = pmax[i];
    __syncthreads();

    float rowmax[16];
#pragma unroll
    for (int i = 0; i < 16; ++i)
        rowmax[i] = fmaxf(fmaxf(wredA[0][i], wredA[1][i]),
                          fmaxf(wredA[2][i], wredA[3][i]));

    // pass 2: sum of exp2(s - rowmax)
    float psum[16];
#pragma unroll
    for (int i = 0; i < 16; ++i) psum[i] = 0.0f;
    for (int m = t; m < NF; m += 256) {
        float kx = kpb[3 * m], ky = kpb[3 * m + 1], kz = kpb[3 * m + 2];
#pragma unroll
        for (int i = 0; i < 16; ++i) {
            float s = fmaf(qx[i], kx, fmaf(qy[i], ky, qz[i] * kz));
            psum[i] += EXP2F(s - rowmax[i]);
        }
    }
#pragma unroll
    for (int off = 32; off >= 1; off >>= 1)
#pragma unroll
        for (int i = 0; i < 16; ++i)
            psum[i] += __shfl_xor(psum[i], off, 64);
    if (lane == 0)
#pragma unroll
        for (int i = 0; i < 16; ++i) wredB[wv][i] = psum[i];
    __syncthreads();

    if (t < 16) {
        float m = fmaxf(fmaxf(wredA[0][t], wredA[1][t]),
                        fmaxf(wredA[2][t], wredA[3][t]));
        float l = wredB[0][t] + wredB[1][t] + wredB[2][t] + wredB[3][t];
        int row = b * NQ + q0 + t;
        rstat[row] = make_float2(m, 1.0f / l);
        qp[row].w = -m;             // fold rowmax into the score fma-chain
    }
}

// ---------------------------------------------------------------------------
// Kernel 3 (main): out-tile 128q x 96c per block; wave w owns q-subtile w x
// all 6 c-subtiles (no in-block P duplication). Double-buffered LDS staging,
// XOR-swizzled vT (conflict-free), kp tight-float3 broadcast reads.
// ---------------------------------------------------------------------------
__global__ __launch_bounds__(THR, 4) void attn_mfma_kernel(
    const float* __restrict__ v, const float4* __restrict__ qp,
    const float* __restrict__ kp3, const float2* __restrict__ rstat,
    float* __restrict__ out)
{
    // vT: 96 c-rows x 68 dwords (64 k-pair dwords + pad), k-index XOR-swizzled
    __shared__ unsigned int vTd[2][CT * 68];
    __shared__ float4 kplB[2][96];   // 128 tight-float3 entries = 96 float4

    const int t    = threadIdx.x;
    const int bid  = blockIdx.x;
    // XCD-swizzle: q-tiles of the same (b, ct) land on one XCD
    const int g    = (bid & 7) + 8 * ((bid >> 3) & 3);  // 0..31 -> (b, ct)
    const int qt   = bid >> 5;                          // 0..15
    const int b    = g >> 3;
    const int ct   = g & 7;

    const int lane = t & 63;
    const int wv   = t >> 6;        // wave 0..7 owns q-subtile wv
    const int quad = lane >> 4;
    const int l15  = lane & 15;

    const int qrow0 = b * NQ + qt * QT;
    const int cbase = ct * CT;

    // this lane's A-row: q = qrow0 + wv*16 + l15. qp.w already = -rowmax'.
    float4 qv = qp[qrow0 + wv * 16 + l15];
    const float qx = qv.x, qy = qv.y, qz = qv.z, qw = qv.w;

    // staging mapping (v): thread -> (row-pair rp, float4-col c4l + 8*rep)
    const int rp  = (t & 7) + 8 * wv;       // 0..63
    const int c4l = (t >> 3) & 7;           // 0..7

    const float*  vb   = v + (size_t)b * NF * CC + cbase;
    const float4* kp4g = (const float4*)(kp3 + (size_t)b * NF * 3);

    floatx4 acc[6];
#pragma unroll
    for (int cs = 0; cs < 6; ++cs) acc[cs] = (floatx4){0.f, 0.f, 0.f, 0.f};

    float va0[3][4], va1[3][4];
    float4 kpld = make_float4(0.f, 0.f, 0.f, 0.f);

    // ---- load chunk 0 into registers ----
#pragma unroll
    for (int rep = 0; rep < 3; ++rep) {
        int col = 4 * (c4l + 8 * rep);
        const float4* p0 = (const float4*)(vb + (size_t)(2 * rp) * CC + col);
        float4 a = p0[0];
        float4 bq = p0[CC / 4];
        va0[rep][0] = a.x;  va0[rep][1] = a.y;  va0[rep][2] = a.z;  va0[rep][3] = a.w;
        va1[rep][0] = bq.x; va1[rep][1] = bq.y; va1[rep][2] = bq.z; va1[rep][3] = bq.w;
    }
    if (t < 96) kpld = kp4g[t];

    for (int ch = 0; ch < NCH; ++ch) {
        const int p = ch & 1;

        // ---- store staged chunk to LDS buffer p ----
#pragma unroll
        for (int rep = 0; rep < 3; ++rep) {
            int c0 = 4 * (c4l + 8 * rep);
#pragma unroll
            for (int w = 0; w < 4; ++w) {
                unsigned int pk = f2bf(va0[rep][w]) | (f2bf(va1[rep][w]) << 16);
                vTd[p][(c0 + w) * 68 + (rp ^ (4 * c4l))] = pk;
            }
        }
        if (t < 96) kplB[p][t] = kpld;
        __syncthreads();

        // ---- prefetch next chunk into registers ----
        if (ch + 1 < NCH) {
            int m0 = (ch + 1) * BK;
#pragma unroll
            for (int rep = 0; rep < 3; ++rep) {
                int col = 4 * (c4l + 8 * rep);
                const float4* p0 = (const float4*)(vb + (size_t)(m0 + 2 * rp) * CC + col);
                float4 a = p0[0];
                float4 bq = p0[CC / 4];
                va0[rep][0] = a.x;  va0[rep][1] = a.y;  va0[rep][2] = a.z;  va0[rep][3] = a.w;
                va1[rep][0] = bq.x; va1[rep][1] = bq.y; va1[rep][2] = bq.z; va1[rep][3] = bq.w;
            }
            if (t < 96) kpld = kp4g[(ch + 1) * 96 + t];
        }

        // ---- compute 4 K32 steps from buffer p ----
#pragma unroll
        for (int kk = 0; kk < BK; kk += 32) {
            // kp for this lane's 8 k's: 24 contiguous dwords, quad-broadcast
            union { float4 v4[6]; float f[24]; } kq;
            const int kb4 = (kk * 3) / 4 + 6 * quad;   // {0,24,48,72}/4*3 + 6q
#pragma unroll
            for (int i = 0; i < 6; ++i) kq.v4[i] = kplB[p][kb4 + i];

            // A-fragment: p = exp2(dot3 + qw), packed bf16 pairs
            union { short8 s; unsigned int d[4]; } af;
#pragma unroll
            for (int j = 0; j < 8; j += 2) {
                float s0 = fmaf(qx, kq.f[3 * j],
                           fmaf(qy, kq.f[3 * j + 1],
                           fmaf(qz, kq.f[3 * j + 2], qw)));
                float s1 = fmaf(qx, kq.f[3 * j + 3],
                           fmaf(qy, kq.f[3 * j + 4],
                           fmaf(qz, kq.f[3 * j + 5], qw)));
                af.d[j >> 1] = f2bf(EXP2F(s0)) | (f2bf(EXP2F(s1)) << 16);
            }

            // B-fragments from swizzled vT + MFMA
#pragma unroll
            for (int cs = 0; cs < 6; ++cs) {
                int c  = cs * 16 + l15;
                int d0 = ((kk >> 1) + 4 * quad) ^ (4 * ((c >> 2) & 7));
                union { uint4 u; short8 s; } bw;
                bw.u = *(const uint4*)&vTd[p][c * 68 + d0];
                acc[cs] = __builtin_amdgcn_mfma_f32_16x16x32_bf16(
                    af.s, bw.s, acc[cs], 0, 0, 0);
            }
        }
        __syncthreads();   // all waves done reading buf p before its reuse
    }

    // ---- epilogue: normalize (linv) and store ----
#pragma unroll
    for (int vv = 0; vv < 4; ++vv) {
        int row = qrow0 + wv * 16 + quad * 4 + vv;
        float lv = rstat[row].y;
        float* orow = out + (size_t)row * CC + cbase + l15;
#pragma unroll
        for (int cs = 0; cs < 6; ++cs)
            orow[cs * 16] = acc[cs][vv] * lv;
    }
}

// ---------------------------------------------------------------------------
extern "C" void kernel_launch(void* const* d_in, const int* in_sizes, int n_in,
                              void* d_out, int out_size, void* d_ws, size_t ws_size,
                              hipStream_t stream) {
    const float* q  = (const float*)d_in[0];
    const float* k  = (const float*)d_in[1];
    const float* v  = (const float*)d_in[2];
    const float* W1 = (const float*)d_in[3];
    const float* b1 = (const float*)d_in[4];
    const float* W2 = (const float*)d_in[5];
    const float* b2 = (const float*)d_in[6];
    float* out = (float*)d_out;

    // ws layout: kp3 tight (768 KiB) | qp (128 KiB) | rstat (64 KiB)
    float*  kp3   = (float*)d_ws;
    float4* qpW   = (float4*)((char*)d_ws + (size_t)Bt * NF * 3 * 4);
    float2* rstat = (float2*)((char*)d_ws + (size_t)Bt * NF * 3 * 4 + (size_t)Bt * NQ * 16);

    hipLaunchKernelGGL(prep_kernel, dim3((Bt * NQ + Bt * NF) / 256), dim3(256), 0, stream,
                       q, k, W1, b1, W2, b2, qpW, kp3);
    hipLaunchKernelGGL(stats_kernel, dim3(Bt * (NQ / 16)), dim3(256), 0, stream,
                       qpW, kp3, rstat);
    hipLaunchKernelGGL(attn_mfma_kernel, dim3(Bt * (NQ / QT) * (CC / CT)), dim3(THR), 0, stream,
                       v, qpW, kp3, rstat, out);
}